// Round 5
// baseline (769.869 us; speedup 1.0000x reference)
//
#include <hip/hip_runtime.h>
#include <hip/hip_bf16.h>

#define N_ROWS 8192
#define DIM 512
#define SCALE 2.659f
#define MAXLOGIT 2.659f
#define NCHUNK 16
#define CHUNK 512
#define BM 128
#define BN 128
#define NLAB 128
#define CS_DIMS 32
#define LOG2E 1.44269504f

typedef __attribute__((ext_vector_type(8))) short short8;
typedef __attribute__((ext_vector_type(4))) float f32x4;

__device__ __forceinline__ unsigned short f2bf(float f) {
    unsigned int u = __float_as_uint(f);
    u += 0x7fffu + ((u >> 16) & 1u);
    return (unsigned short)(u >> 16);
}
__device__ __forceinline__ float bflo(unsigned int u) { return __uint_as_float(u << 16); }
__device__ __forceinline__ float bfhi(unsigned int u) { return __uint_as_float(u & 0xffff0000u); }
__device__ __forceinline__ float bf1(unsigned short u) { return __uint_as_float((unsigned)u << 16); }

// ---------------------------------------------------------------- normalize
__global__ __launch_bounds__(256) void norm_cast_kernel(
    const float* __restrict__ text, const float* __restrict__ image,
    unsigned short* __restrict__ imgn, unsigned short* __restrict__ txtn)
{
    int row  = blockIdx.x * 4 + (threadIdx.x >> 6);
    int lane = threadIdx.x & 63;
    const float* src;
    unsigned short* dst;
    if (row < N_ROWS) { src = image + (size_t)row * DIM; dst = imgn + (size_t)row * DIM; }
    else { int r = row - N_ROWS; src = text + (size_t)r * DIM; dst = txtn + (size_t)r * DIM; }
    const float4* s4 = (const float4*)src + lane * 2;
    float4 a = s4[0], b = s4[1];
    float ss = a.x*a.x + a.y*a.y + a.z*a.z + a.w*a.w
             + b.x*b.x + b.y*b.y + b.z*b.z + b.w*b.w;
    #pragma unroll
    for (int m = 1; m < 64; m <<= 1) ss += __shfl_xor(ss, m, 64);
    float sc = 1.0f / fmaxf(sqrtf(ss), 1e-12f);
    uint4 o;
    o.x = (unsigned)f2bf(a.x*sc) | ((unsigned)f2bf(a.y*sc) << 16);
    o.y = (unsigned)f2bf(a.z*sc) | ((unsigned)f2bf(a.w*sc) << 16);
    o.z = (unsigned)f2bf(b.x*sc) | ((unsigned)f2bf(b.y*sc) << 16);
    o.w = (unsigned)f2bf(b.z*sc) | ((unsigned)f2bf(b.w*sc) << 16);
    *((uint4*)dst + lane) = o;
}

// ---------------------------------------------------------------- histogram
__global__ __launch_bounds__(256) void hist_kernel(
    const int* __restrict__ labels, int* __restrict__ hist_g)
{
    __shared__ int hist[NLAB];
    int tid = threadIdx.x;
    if (tid < NLAB) hist[tid] = 0;
    __syncthreads();
    for (int i = tid; i < N_ROWS; i += 256) {
        int lb = labels[i];
        if (lb >= 0 && lb < NLAB) atomicAdd(&hist[lb], 1);
    }
    __syncthreads();
    if (tid < NLAB) hist_g[tid] = hist[tid];
}

// ---------------------------------------------------------------- class sums
// grid: 2 dirs x 16 dim-slices. Each block streams all rows once,
// LDS-atomic accumulating cs[label][dim] for its 32-dim slice.
// bank = dim -> conflict-free (2-way across the two rows of a wave: free).
__global__ __launch_bounds__(256) void classsum_kernel(
    const unsigned short* __restrict__ imgn, const unsigned short* __restrict__ txtn,
    const int* __restrict__ labels, float* __restrict__ csum)
{
    __shared__ float cs[NLAB * CS_DIMS];   // 16 KB
    int dir = blockIdx.x >> 4;
    int d0  = (blockIdx.x & 15) * CS_DIMS;
    const unsigned short* src = dir ? imgn : txtn;
    int tid  = threadIdx.x;
    int dim  = tid & 31;
    int rgrp = tid >> 5;
    for (int i = tid; i < NLAB * CS_DIMS; i += 256) cs[i] = 0.f;
    __syncthreads();
    for (int row = rgrp; row < N_ROWS; row += 8) {
        int lab = labels[row];
        if (lab >= 0) {
            float v = bf1(src[(size_t)row * DIM + d0 + dim]);
            atomicAdd(&cs[lab * CS_DIMS + dim], v);
        }
    }
    __syncthreads();
    for (int i = tid; i < NLAB * CS_DIMS; i += 256) {
        int lab = i >> 5, d = i & 31;
        csum[((size_t)dir * NLAB + lab) * DIM + d0 + d] = cs[i];
    }
}

// ---------------------------------------------------------------- fused GEMM
#define ASYNC16(gp, lp) \
  __builtin_amdgcn_global_load_lds((const __attribute__((address_space(1))) void*)(gp), \
                                   (__attribute__((address_space(3))) void*)(lp), 16, 0, 0)

__global__ __launch_bounds__(256, 3) void gemm_fused_kernel(
    const unsigned short* __restrict__ imgn, const unsigned short* __restrict__ txtn,
    float* __restrict__ part)
{
    __shared__ unsigned short Ald[BM * 32];
    __shared__ unsigned short Bld[BN * 32];
    __shared__ float red[2][BM];

    int bid    = blockIdx.x;
    int dir    = bid >> 10;      // 0: rows=img, 1: rows=txt
    int rem    = bid & 1023;
    int rowblk = rem & 63;
    int chunk  = rem >> 6;       // 0..15
    const unsigned short* A = dir ? txtn : imgn;
    const unsigned short* B = dir ? imgn : txtn;
    int rowBase  = rowblk * BM;
    int colBase0 = chunk * CHUNK;

    int tid  = threadIdx.x;
    int lane = tid & 63;
    int w    = tid >> 6;
    int wr   = w >> 1, wc = w & 1;
    int q    = lane >> 4;
    int lm   = lane & 15;

    float s_acc[16];
    #pragma unroll
    for (int i = 0; i < 16; ++i) s_acc[i] = 0.f;

    // Swizzled LDS layout: within each 16-row group, LDS[row][slot] holds
    // k-block (slot ^ ((row>>1)&3)) of that row. Any 8 consecutive reader
    // lanes then tile all 32 banks: block(lm) = 4*(lm&1) + (q ^ ((lm>>1)&3)).
    int srow  = lane >> 2;                                   // row within group
    int spart = ((lane & 3) ^ ((lane >> 3) & 3)) * 8;        // staged k-block
    int qx    = (q ^ ((lm >> 1) & 3)) * 8;                   // read slot

    const float C1 = SCALE * LOG2E;
    const float C2 = -MAXLOGIT * LOG2E;

    for (int tile = 0; tile < CHUNK / BN; ++tile) {
        int colBase = colBase0 + tile * BN;
        f32x4 acc[4][4];
        #pragma unroll
        for (int mi = 0; mi < 4; ++mi)
          #pragma unroll
          for (int ni = 0; ni < 4; ++ni)
            acc[mi][ni] = (f32x4){0.f, 0.f, 0.f, 0.f};

        for (int kt = 0; kt < DIM / 32; ++kt) {
            int k0 = kt * 32;
            __syncthreads();   // all waves done reading LDS before re-stage
            #pragma unroll
            for (int i = 0; i < 2; ++i) {
                int rlocal = i*64 + w*16 + srow;
                ASYNC16(A + (size_t)(rowBase + rlocal) * DIM + k0 + spart,
                        Ald + (i*64 + w*16) * 32);
                ASYNC16(B + (size_t)(colBase + rlocal) * DIM + k0 + spart,
                        Bld + (i*64 + w*16) * 32);
            }
            __syncthreads();   // drains vmcnt(0): staging complete

            short8 af[4], bf[4];
            #pragma unroll
            for (int mi = 0; mi < 4; ++mi)
                af[mi] = *(const short8*)(Ald + (wr*64 + mi*16 + lm)*32 + qx);
            #pragma unroll
            for (int ni = 0; ni < 4; ++ni)
                bf[ni] = *(const short8*)(Bld + (wc*64 + ni*16 + lm)*32 + qx);
            #pragma unroll
            for (int mi = 0; mi < 4; ++mi)
              #pragma unroll
              for (int ni = 0; ni < 4; ++ni)
                acc[mi][ni] = __builtin_amdgcn_mfma_f32_16x16x32_bf16(
                                  af[mi], bf[ni], acc[mi][ni], 0, 0, 0);
        }

        // epilogue: exp-sum only (fixed max 2.659); d handled via class sums
        #pragma unroll
        for (int ni = 0; ni < 4; ++ni)
          #pragma unroll
          for (int mi = 0; mi < 4; ++mi)
            #pragma unroll
            for (int r = 0; r < 4; ++r)
              s_acc[mi*4 + r] += __builtin_amdgcn_exp2f(
                                    __fmaf_rn(acc[mi][ni][r], C1, C2));
    }

    // reduce across the 16 column-lanes (low 4 lane bits)
    #pragma unroll
    for (int idx = 0; idx < 16; ++idx) {
        float s = s_acc[idx];
        #pragma unroll
        for (int m = 1; m < 16; m <<= 1) s += __shfl_xor(s, m, 64);
        s_acc[idx] = s;
    }
    if (lm == 0) {
        #pragma unroll
        for (int idx = 0; idx < 16; ++idx) {
            int rl = wr*64 + (idx>>2)*16 + q*4 + (idx&3);
            red[wc][rl] = s_acc[idx];
        }
    }
    __syncthreads();
    if (tid < BM)
        part[(size_t)(dir * NCHUNK + chunk) * N_ROWS + rowBase + tid]
            = red[0][tid] + red[1][tid];
}

// ---------------------------------------------------------------- loss stage 1
// one wave per (dir, i): dot(a_i, c_{lab_i}) (or a_i . b_i if lab<0) + lse merge
__global__ __launch_bounds__(256) void loss_stage1_kernel(
    const unsigned short* __restrict__ imgn, const unsigned short* __restrict__ txtn,
    const int* __restrict__ labels, const float* __restrict__ part,
    const float* __restrict__ csum, const int* __restrict__ hist,
    float* __restrict__ partial)
{
    __shared__ float wsum[4];
    int w    = threadIdx.x >> 6;
    int lane = threadIdx.x & 63;
    int wid  = blockIdx.x * 4 + w;
    int dir  = wid >> 13;
    int i    = wid & (N_ROWS - 1);
    int lab  = labels[i];

    const unsigned short* arow = (dir ? txtn : imgn) + (size_t)i * DIM;
    uint4 av = ((const uint4*)arow)[lane];
    float a0 = bflo(av.x), a1 = bfhi(av.x), a2 = bflo(av.y), a3 = bfhi(av.y);
    float a4 = bflo(av.z), a5 = bfhi(av.z), a6 = bflo(av.w), a7 = bfhi(av.w);

    float dot;
    if (lab < 0) {
        const unsigned short* brow = (dir ? imgn : txtn) + (size_t)i * DIM;
        uint4 bv = ((const uint4*)brow)[lane];
        dot = a0*bflo(bv.x) + a1*bfhi(bv.x) + a2*bflo(bv.y) + a3*bfhi(bv.y)
            + a4*bflo(bv.z) + a5*bfhi(bv.z) + a6*bflo(bv.w) + a7*bfhi(bv.w);
    } else {
        const float4* crow = (const float4*)(csum + ((size_t)dir * NLAB + lab) * DIM);
        float4 c0 = crow[lane * 2], c1 = crow[lane * 2 + 1];
        dot = a0*c0.x + a1*c0.y + a2*c0.z + a3*c0.w
            + a4*c1.x + a5*c1.y + a6*c1.z + a7*c1.w;
    }

    float s = (lane < NCHUNK)
            ? part[((size_t)dir * NCHUNK + lane) * N_ROWS + i] : 0.f;
    #pragma unroll
    for (int m = 1; m < 64; m <<= 1) {
        dot += __shfl_xor(dot, m, 64);
        s   += __shfl_xor(s,   m, 64);
    }
    if (lane == 0) {
        float sumT = (lab < 0) ? 1.0f : (float)hist[lab];
        wsum[w] = (MAXLOGIT + __logf(s)) - SCALE * dot / sumT;
    }
    __syncthreads();
    if (threadIdx.x == 0)
        partial[blockIdx.x] = wsum[0] + wsum[1] + wsum[2] + wsum[3];
}

// ---------------------------------------------------------------- loss stage 2
__global__ __launch_bounds__(256) void loss_stage2_kernel(
    const float* __restrict__ partial, float* __restrict__ out)
{
    __shared__ float ws[4];
    int tid = threadIdx.x, lane = tid & 63;
    float v = 0.f;
    for (int k = tid; k < 2 * N_ROWS / 4; k += 256) v += partial[k];
    #pragma unroll
    for (int m = 1; m < 64; m <<= 1) v += __shfl_xor(v, m, 64);
    if (lane == 0) ws[tid >> 6] = v;
    __syncthreads();
    if (tid == 0) out[0] = (ws[0] + ws[1] + ws[2] + ws[3]) * (1.0f / (2 * N_ROWS));
}

// ---------------------------------------------------------------- launch
extern "C" void kernel_launch(void* const* d_in, const int* in_sizes, int n_in,
                              void* d_out, int out_size, void* d_ws, size_t ws_size,
                              hipStream_t stream)
{
    const float* text   = (const float*)d_in[0];
    const float* image  = (const float*)d_in[1];
    const int*   labels = (const int*)d_in[2];

    unsigned short* imgn = (unsigned short*)d_ws;
    unsigned short* txtn = imgn + (size_t)N_ROWS * DIM;
    char* base = (char*)d_ws + 2 * (size_t)N_ROWS * DIM * sizeof(unsigned short);
    float* part    = (float*)base;                                   // 1 MB
    float* csum    = part + 2 * NCHUNK * (size_t)N_ROWS;             // 256 KB
    int*   hist    = (int*)(csum + 2 * NLAB * DIM);                  // 512 B
    float* partial = (float*)(hist + NLAB);                          // 16 KB
    float* out     = (float*)d_out;

    hipLaunchKernelGGL(norm_cast_kernel, dim3(2 * N_ROWS / 4), dim3(256), 0, stream,
                       text, image, imgn, txtn);
    hipLaunchKernelGGL(hist_kernel, dim3(1), dim3(256), 0, stream, labels, hist);
    hipLaunchKernelGGL(classsum_kernel, dim3(32), dim3(256), 0, stream,
                       imgn, txtn, labels, csum);
    hipLaunchKernelGGL(gemm_fused_kernel, dim3(2 * 64 * NCHUNK), dim3(256), 0, stream,
                       imgn, txtn, part);
    hipLaunchKernelGGL(loss_stage1_kernel, dim3(2 * N_ROWS / 4), dim3(256), 0, stream,
                       imgn, txtn, labels, part, csum, hist, partial);
    hipLaunchKernelGGL(loss_stage2_kernel, dim3(1), dim3(256), 0, stream, partial, out);
}

// Round 6
// 322.869 us; speedup vs baseline: 2.3845x; 2.3845x over previous
//
#include <hip/hip_runtime.h>
#include <hip/hip_bf16.h>

#define N_ROWS 8192
#define DIM 512
#define SCALE 2.659f
#define MAXLOGIT 2.659f
#define NCHUNK 16
#define CHUNK 512
#define BM 128
#define BN 128
#define NLAB 128
#define CS_DSLICE 64
#define CS_ROWS 512
#define LOG2E 1.44269504f

typedef __attribute__((ext_vector_type(8))) short short8;
typedef __attribute__((ext_vector_type(4))) float f32x4;

__device__ __forceinline__ unsigned short f2bf(float f) {
    unsigned int u = __float_as_uint(f);
    u += 0x7fffu + ((u >> 16) & 1u);
    return (unsigned short)(u >> 16);
}
__device__ __forceinline__ float bflo(unsigned int u) { return __uint_as_float(u << 16); }
__device__ __forceinline__ float bfhi(unsigned int u) { return __uint_as_float(u & 0xffff0000u); }

// ---------------------------------------------------------------- normalize
__global__ __launch_bounds__(256) void norm_cast_kernel(
    const float* __restrict__ text, const float* __restrict__ image,
    unsigned short* __restrict__ imgn, unsigned short* __restrict__ txtn)
{
    int row  = blockIdx.x * 4 + (threadIdx.x >> 6);
    int lane = threadIdx.x & 63;
    const float* src;
    unsigned short* dst;
    if (row < N_ROWS) { src = image + (size_t)row * DIM; dst = imgn + (size_t)row * DIM; }
    else { int r = row - N_ROWS; src = text + (size_t)r * DIM; dst = txtn + (size_t)r * DIM; }
    const float4* s4 = (const float4*)src + lane * 2;
    float4 a = s4[0], b = s4[1];
    float ss = a.x*a.x + a.y*a.y + a.z*a.z + a.w*a.w
             + b.x*b.x + b.y*b.y + b.z*b.z + b.w*b.w;
    #pragma unroll
    for (int m = 1; m < 64; m <<= 1) ss += __shfl_xor(ss, m, 64);
    float sc = 1.0f / fmaxf(sqrtf(ss), 1e-12f);
    uint4 o;
    o.x = (unsigned)f2bf(a.x*sc) | ((unsigned)f2bf(a.y*sc) << 16);
    o.y = (unsigned)f2bf(a.z*sc) | ((unsigned)f2bf(a.w*sc) << 16);
    o.z = (unsigned)f2bf(b.x*sc) | ((unsigned)f2bf(b.y*sc) << 16);
    o.w = (unsigned)f2bf(b.z*sc) | ((unsigned)f2bf(b.w*sc) << 16);
    *((uint4*)dst + lane) = o;
}

// ---------------------------------------------------------------- histogram
__global__ __launch_bounds__(256) void hist_kernel(
    const int* __restrict__ labels, int* __restrict__ hist_g)
{
    __shared__ int hist[NLAB];
    int tid = threadIdx.x;
    if (tid < NLAB) hist[tid] = 0;
    __syncthreads();
    for (int i = tid; i < N_ROWS; i += 256) {
        int lb = labels[i];
        if (lb >= 0 && lb < NLAB) atomicAdd(&hist[lb], 1);
    }
    __syncthreads();
    if (tid < NLAB) hist_g[tid] = hist[tid];
}

// ---------------------------------------------------------------- class sums
// grid: 2 dirs x 8 dim-slices(64) x 16 row-chunks(512) = 256 blocks.
// Each thread streams uint4 (8 dims / 16 B) per row -> BW-bound, not
// latency-bound. LDS cs[128][64] accumulate, then global atomicAdd into
// zero-initialized csum.
__global__ __launch_bounds__(256) void classsum_kernel(
    const unsigned short* __restrict__ imgn, const unsigned short* __restrict__ txtn,
    const int* __restrict__ labels, float* __restrict__ csum)
{
    __shared__ float cs[NLAB * CS_DSLICE];   // 32 KB
    __shared__ int   labL[CS_ROWS];          // 2 KB
    int b    = blockIdx.x;
    int dir  = b >> 7;
    int rem  = b & 127;
    int ds   = rem >> 4;                     // 0..7
    int rc   = rem & 15;                     // 0..15
    int d0   = ds * CS_DSLICE;
    int row0 = rc * CS_ROWS;
    const unsigned short* src = dir ? imgn : txtn;
    int tid = threadIdx.x;
    #pragma unroll
    for (int i = 0; i < NLAB * CS_DSLICE / 256; ++i) cs[i * 256 + tid] = 0.f;
    #pragma unroll
    for (int i = 0; i < CS_ROWS / 256; ++i) labL[i * 256 + tid] = labels[row0 + i * 256 + tid];
    __syncthreads();
    int oct  = tid & 7;      // dim octet: dims d0 + oct*8 .. +7
    int rgrp = tid >> 3;     // row group, stride 32
    #pragma unroll 4
    for (int it = 0; it < CS_ROWS / 32; ++it) {
        int r   = rgrp + it * 32;
        int lab = labL[r];
        if (lab >= 0) {
            uint4 v = *(const uint4*)(src + (size_t)(row0 + r) * DIM + d0 + oct * 8);
            float* c = cs + lab * CS_DSLICE + oct * 8;
            atomicAdd(c+0, bflo(v.x)); atomicAdd(c+1, bfhi(v.x));
            atomicAdd(c+2, bflo(v.y)); atomicAdd(c+3, bfhi(v.y));
            atomicAdd(c+4, bflo(v.z)); atomicAdd(c+5, bfhi(v.z));
            atomicAdd(c+6, bflo(v.w)); atomicAdd(c+7, bfhi(v.w));
        }
    }
    __syncthreads();
    #pragma unroll
    for (int i = 0; i < NLAB * CS_DSLICE / 256; ++i) {
        int idx = i * 256 + tid;
        float v = cs[idx];
        if (v != 0.f) {
            int lab = idx >> 6, d = idx & 63;
            atomicAdd(&csum[((size_t)dir * NLAB + lab) * DIM + d0 + d], v);
        }
    }
}

// ---------------------------------------------------------------- fused GEMM
#define ASYNC16(gp, lp) \
  __builtin_amdgcn_global_load_lds((const __attribute__((address_space(1))) void*)(gp), \
                                   (__attribute__((address_space(3))) void*)(lp), 16, 0, 0)

__global__ __launch_bounds__(256, 3) void gemm_fused_kernel(
    const unsigned short* __restrict__ imgn, const unsigned short* __restrict__ txtn,
    float* __restrict__ part)
{
    __shared__ unsigned short Ald[BM * 32];
    __shared__ unsigned short Bld[BN * 32];
    __shared__ float red[2][BM];

    int bid    = blockIdx.x;
    int dir    = bid >> 10;      // 0: rows=img, 1: rows=txt
    int rem    = bid & 1023;
    int rowblk = rem & 63;
    int chunk  = rem >> 6;       // 0..15
    const unsigned short* A = dir ? txtn : imgn;
    const unsigned short* B = dir ? imgn : txtn;
    int rowBase  = rowblk * BM;
    int colBase0 = chunk * CHUNK;

    int tid  = threadIdx.x;
    int lane = tid & 63;
    int w    = tid >> 6;
    int wr   = w >> 1, wc = w & 1;
    int q    = lane >> 4;
    int lm   = lane & 15;

    float s_acc[16];
    #pragma unroll
    for (int i = 0; i < 16; ++i) s_acc[i] = 0.f;

    // Swizzled LDS layout: within each 16-row group, LDS[row][slot] holds
    // k-block (slot ^ ((row>>1)&3)) of that row. Any 8 consecutive reader
    // lanes then tile all 32 banks.
    int srow  = lane >> 2;                                   // row within group
    int spart = ((lane & 3) ^ ((lane >> 3) & 3)) * 8;        // staged k-block
    int qx    = (q ^ ((lm >> 1) & 3)) * 8;                   // read slot

    const float C1 = SCALE * LOG2E;
    const float C2 = -MAXLOGIT * LOG2E;

    for (int tile = 0; tile < CHUNK / BN; ++tile) {
        int colBase = colBase0 + tile * BN;
        f32x4 acc[4][4];
        #pragma unroll
        for (int mi = 0; mi < 4; ++mi)
          #pragma unroll
          for (int ni = 0; ni < 4; ++ni)
            acc[mi][ni] = (f32x4){0.f, 0.f, 0.f, 0.f};

        for (int kt = 0; kt < DIM / 32; ++kt) {
            int k0 = kt * 32;
            __syncthreads();   // all waves done reading LDS before re-stage
            #pragma unroll
            for (int i = 0; i < 2; ++i) {
                int rlocal = i*64 + w*16 + srow;
                ASYNC16(A + (size_t)(rowBase + rlocal) * DIM + k0 + spart,
                        Ald + (i*64 + w*16) * 32);
                ASYNC16(B + (size_t)(colBase + rlocal) * DIM + k0 + spart,
                        Bld + (i*64 + w*16) * 32);
            }
            __syncthreads();   // drains vmcnt(0): staging complete

            short8 af[4], bf[4];
            #pragma unroll
            for (int mi = 0; mi < 4; ++mi)
                af[mi] = *(const short8*)(Ald + (wr*64 + mi*16 + lm)*32 + qx);
            #pragma unroll
            for (int ni = 0; ni < 4; ++ni)
                bf[ni] = *(const short8*)(Bld + (wc*64 + ni*16 + lm)*32 + qx);
            #pragma unroll
            for (int mi = 0; mi < 4; ++mi)
              #pragma unroll
              for (int ni = 0; ni < 4; ++ni)
                acc[mi][ni] = __builtin_amdgcn_mfma_f32_16x16x32_bf16(
                                  af[mi], bf[ni], acc[mi][ni], 0, 0, 0);
        }

        // epilogue: exp-sum only (fixed max 2.659); d handled via class sums
        #pragma unroll
        for (int ni = 0; ni < 4; ++ni)
          #pragma unroll
          for (int mi = 0; mi < 4; ++mi)
            #pragma unroll
            for (int r = 0; r < 4; ++r)
              s_acc[mi*4 + r] += __builtin_amdgcn_exp2f(
                                    __fmaf_rn(acc[mi][ni][r], C1, C2));
    }

    // reduce across the 16 column-lanes (low 4 lane bits)
    #pragma unroll
    for (int idx = 0; idx < 16; ++idx) {
        float s = s_acc[idx];
        #pragma unroll
        for (int m = 1; m < 16; m <<= 1) s += __shfl_xor(s, m, 64);
        s_acc[idx] = s;
    }
    if (lm == 0) {
        #pragma unroll
        for (int idx = 0; idx < 16; ++idx) {
            int rl = wr*64 + (idx>>2)*16 + q*4 + (idx&3);
            red[wc][rl] = s_acc[idx];
        }
    }
    __syncthreads();
    if (tid < BM)
        part[(size_t)(dir * NCHUNK + chunk) * N_ROWS + rowBase + tid]
            = red[0][tid] + red[1][tid];
}

// ---------------------------------------------------------------- loss stage 1
// one wave per (dir, i): dot(a_i, c_{lab_i}) (or a_i . b_i if lab<0) + lse merge
__global__ __launch_bounds__(256) void loss_stage1_kernel(
    const unsigned short* __restrict__ imgn, const unsigned short* __restrict__ txtn,
    const int* __restrict__ labels, const float* __restrict__ part,
    const float* __restrict__ csum, const int* __restrict__ hist,
    float* __restrict__ partial)
{
    __shared__ float wsum[4];
    int w    = threadIdx.x >> 6;
    int lane = threadIdx.x & 63;
    int wid  = blockIdx.x * 4 + w;
    int dir  = wid >> 13;
    int i    = wid & (N_ROWS - 1);
    int lab  = labels[i];

    const unsigned short* arow = (dir ? txtn : imgn) + (size_t)i * DIM;
    uint4 av = ((const uint4*)arow)[lane];
    float a0 = bflo(av.x), a1 = bfhi(av.x), a2 = bflo(av.y), a3 = bfhi(av.y);
    float a4 = bflo(av.z), a5 = bfhi(av.z), a6 = bflo(av.w), a7 = bfhi(av.w);

    float dot;
    if (lab < 0) {
        const unsigned short* brow = (dir ? imgn : txtn) + (size_t)i * DIM;
        uint4 bv = ((const uint4*)brow)[lane];
        dot = a0*bflo(bv.x) + a1*bfhi(bv.x) + a2*bflo(bv.y) + a3*bfhi(bv.y)
            + a4*bflo(bv.z) + a5*bfhi(bv.z) + a6*bflo(bv.w) + a7*bfhi(bv.w);
    } else {
        const float4* crow = (const float4*)(csum + ((size_t)dir * NLAB + lab) * DIM);
        float4 c0 = crow[lane * 2], c1 = crow[lane * 2 + 1];
        dot = a0*c0.x + a1*c0.y + a2*c0.z + a3*c0.w
            + a4*c1.x + a5*c1.y + a6*c1.z + a7*c1.w;
    }

    float s = (lane < NCHUNK)
            ? part[((size_t)dir * NCHUNK + lane) * N_ROWS + i] : 0.f;
    #pragma unroll
    for (int m = 1; m < 64; m <<= 1) {
        dot += __shfl_xor(dot, m, 64);
        s   += __shfl_xor(s,   m, 64);
    }
    if (lane == 0) {
        float sumT = (lab < 0) ? 1.0f : (float)hist[lab];
        wsum[w] = (MAXLOGIT + __logf(s)) - SCALE * dot / sumT;
    }
    __syncthreads();
    if (threadIdx.x == 0)
        partial[blockIdx.x] = wsum[0] + wsum[1] + wsum[2] + wsum[3];
}

// ---------------------------------------------------------------- loss stage 2
__global__ __launch_bounds__(256) void loss_stage2_kernel(
    const float* __restrict__ partial, float* __restrict__ out)
{
    __shared__ float ws[4];
    int tid = threadIdx.x, lane = tid & 63;
    float v = 0.f;
    for (int k = tid; k < 2 * N_ROWS / 4; k += 256) v += partial[k];
    #pragma unroll
    for (int m = 1; m < 64; m <<= 1) v += __shfl_xor(v, m, 64);
    if (lane == 0) ws[tid >> 6] = v;
    __syncthreads();
    if (tid == 0) out[0] = (ws[0] + ws[1] + ws[2] + ws[3]) * (1.0f / (2 * N_ROWS));
}

// ---------------------------------------------------------------- launch
extern "C" void kernel_launch(void* const* d_in, const int* in_sizes, int n_in,
                              void* d_out, int out_size, void* d_ws, size_t ws_size,
                              hipStream_t stream)
{
    const float* text   = (const float*)d_in[0];
    const float* image  = (const float*)d_in[1];
    const int*   labels = (const int*)d_in[2];

    unsigned short* imgn = (unsigned short*)d_ws;
    unsigned short* txtn = imgn + (size_t)N_ROWS * DIM;
    char* base = (char*)d_ws + 2 * (size_t)N_ROWS * DIM * sizeof(unsigned short);
    float* part    = (float*)base;                                   // 1 MB
    float* csum    = part + 2 * NCHUNK * (size_t)N_ROWS;             // 256 KB
    int*   hist    = (int*)(csum + 2 * NLAB * DIM);                  // 512 B
    float* partial = (float*)(hist + NLAB);                          // 16 KB
    float* out     = (float*)d_out;

    hipLaunchKernelGGL(norm_cast_kernel, dim3(2 * N_ROWS / 4), dim3(256), 0, stream,
                       text, image, imgn, txtn);
    hipLaunchKernelGGL(hist_kernel, dim3(1), dim3(256), 0, stream, labels, hist);
    hipMemsetAsync(csum, 0, 2 * NLAB * DIM * sizeof(float), stream);
    hipLaunchKernelGGL(classsum_kernel, dim3(256), dim3(256), 0, stream,
                       imgn, txtn, labels, csum);
    hipLaunchKernelGGL(gemm_fused_kernel, dim3(2 * 64 * NCHUNK), dim3(256), 0, stream,
                       imgn, txtn, part);
    hipLaunchKernelGGL(loss_stage1_kernel, dim3(2 * N_ROWS / 4), dim3(256), 0, stream,
                       imgn, txtn, labels, part, csum, hist, partial);
    hipLaunchKernelGGL(loss_stage2_kernel, dim3(1), dim3(256), 0, stream, partial, out);
}